// Round 2
// baseline (23551.074 us; speedup 1.0000x reference)
//
#include <hip/hip_runtime.h>
#include <stdint.h>

#define B_ 64
#define T_ 256
#define H_ 1024
#define L_ 4
#define O_ 1024
#define LN_EPS 1e-5f

typedef short v8s __attribute__((ext_vector_type(8)));
typedef float v4f __attribute__((ext_vector_type(4)));

__device__ __forceinline__ unsigned short f2bf(float f) {
  union { float f; unsigned u; } v; v.f = f;
  unsigned r = (v.u + 0x7FFFu + ((v.u >> 16) & 1u)) >> 16;  // RNE
  return (unsigned short)r;
}
__device__ __forceinline__ float bf2f(unsigned short u) {
  union { unsigned u; float f; } v; v.u = ((unsigned)u) << 16; return v.f;
}
__device__ __forceinline__ float tanh_fast(float x) {
  float e = __expf(2.0f * x);
  return 1.0f - 2.0f / (e + 1.0f);   // -> -1/+1 correctly at +-inf
}

// Swizzled LDS index helpers. g ^ (g>>4) mixes high granule bits (lane-varying
// for column-chunked access) into bank bits; ^row breaks row-stride degeneracy.
// Both are bijective per row -> no aliasing. Worst case 2-way (free, m136).
__device__ __forceinline__ int zswz(int row, int gq) {   // float index, 16B granules
  return ((row << 8) + ((gq ^ (gq >> 4) ^ row) & 255)) << 2;
}
__device__ __forceinline__ int hswz(int row, int kq) {   // short index, 16B granules
  return ((row << 7) + ((kq ^ (kq >> 4) ^ row) & 127)) << 3;
}

// ---------------- fp32 -> bf16 bulk convert (vec4) ----------------
__global__ void k_f2b(const float* __restrict__ src, unsigned short* __restrict__ dst, int n4) {
  int i = blockIdx.x * blockDim.x + threadIdx.x;
  int stride = gridDim.x * blockDim.x;
  for (; i < n4; i += stride) {
    float4 v = *(const float4*)(src + 4 * (size_t)i);
    union { unsigned short u[4]; uint2 q; } p;
    p.u[0] = f2bf(v.x); p.u[1] = f2bf(v.y); p.u[2] = f2bf(v.z); p.u[3] = f2bf(v.w);
    *(uint2*)(dst + 4 * (size_t)i) = p.q;
  }
}

// ------------- input [B][T][H] f32 -> X [T][B][H] bf16 -------------
__global__ void k_prep_x(const float* __restrict__ in, unsigned short* __restrict__ X) {
  int row = blockIdx.x;            // row = b*T + t
  int b = row >> 8, t = row & 255;
  const float* src = in + (size_t)row * H_;
  unsigned short* dst = X + ((size_t)t * B_ + b) * H_;
  for (int j = threadIdx.x; j < H_ / 4; j += blockDim.x) {
    float4 v = *(const float4*)(src + 4 * j);
    union { unsigned short u[4]; uint2 q; } p;
    p.u[0] = f2bf(v.x); p.u[1] = f2bf(v.y); p.u[2] = f2bf(v.z); p.u[3] = f2bf(v.w);
    *(uint2*)(dst + 4 * j) = p.q;
  }
}

// ---------------- bf16 GEMM: C[M=16384][1024] = X @ W^T + bias ----------------
__launch_bounds__(256, 2)
__global__ void k_gemm(const unsigned short* __restrict__ Xb,
                       const unsigned short* __restrict__ Wb,
                       const float* __restrict__ bias,
                       float* __restrict__ Cout, int swap_rows) {
  __shared__ short As[128][40];
  __shared__ short Bs[128][40];
  int bm = blockIdx.x >> 3, bn = blockIdx.x & 7;
  int row0 = bm * 128, col0 = bn * 128;
  int tid = threadIdx.x, lane = tid & 63, w = tid >> 6;
  int wm = w >> 1, wn = w & 1;
  int m15 = lane & 15, quad = lane >> 4;
  v4f acc[4][4];
  #pragma unroll
  for (int a = 0; a < 4; ++a)
    #pragma unroll
    for (int b = 0; b < 4; ++b) acc[a][b] = (v4f){0.f, 0.f, 0.f, 0.f};

  int srow = tid >> 1, sseg = tid & 1;
  const unsigned short* gA = Xb + (size_t)(row0 + srow) * 1024 + sseg * 16;
  const unsigned short* gB = Wb + (size_t)(col0 + srow) * 1024 + sseg * 16;

  for (int kb = 0; kb < 32; ++kb) {
    v8s a0 = *(const v8s*)(gA + kb * 32);
    v8s a1 = *(const v8s*)(gA + kb * 32 + 8);
    v8s b0 = *(const v8s*)(gB + kb * 32);
    v8s b1 = *(const v8s*)(gB + kb * 32 + 8);
    *(v8s*)&As[srow][sseg * 16]     = a0;
    *(v8s*)&As[srow][sseg * 16 + 8] = a1;
    *(v8s*)&Bs[srow][sseg * 16]     = b0;
    *(v8s*)&Bs[srow][sseg * 16 + 8] = b1;
    __syncthreads();
    v8s af[4], bfr[4];
    #pragma unroll
    for (int mt = 0; mt < 4; ++mt) af[mt]  = *(v8s*)&As[wm * 64 + mt * 16 + m15][quad * 8];
    #pragma unroll
    for (int nt = 0; nt < 4; ++nt) bfr[nt] = *(v8s*)&Bs[wn * 64 + nt * 16 + m15][quad * 8];
    #pragma unroll
    for (int mt = 0; mt < 4; ++mt)
      #pragma unroll
      for (int nt = 0; nt < 4; ++nt)
        acc[mt][nt] = __builtin_amdgcn_mfma_f32_16x16x32_bf16(af[mt], bfr[nt], acc[mt][nt], 0, 0, 0);
    __syncthreads();
  }
  #pragma unroll
  for (int mt = 0; mt < 4; ++mt) {
    #pragma unroll
    for (int nt = 0; nt < 4; ++nt) {
      int col = col0 + wn * 64 + nt * 16 + m15;
      float bv = bias[col];
      #pragma unroll
      for (int r = 0; r < 4; ++r) {
        int row = row0 + wm * 64 + mt * 16 + quad * 4 + r;
        int orow = swap_rows ? ((row & 63) * 256 + (row >> 6)) : row;
        Cout[(size_t)orow * 1024 + col] = acc[mt][nt][r] + bv;
      }
    }
  }
}

// ---------------- persistent recurrent kernel (one layer) ----------------
// 64 WGs = 4 row-blocks(16 rows) x 16 col-blocks(64 cols).
// Wh fragments resident in VGPRs. z + flags exchanged via agent-scope atomics
// (write-through past non-coherent L2s -> L3). NO fences: keeps A/Wh/Xn cached
// and removes per-step buffer_wbl2 / buffer_inv from the critical path.
__launch_bounds__(256, 1)
__global__ void k_recur(const float* __restrict__ A,            // [T][B][H] fp32 (x@Wx^T + bx)
                        const unsigned short* __restrict__ Whb, // [H][H] bf16, this layer
                        const float* __restrict__ lng, const float* __restrict__ lnb,
                        float* Z,                               // [4 rb][2 par][16][1024] fp32
                        int* flags,                             // [64]: flag[rb*16+cb], this layer
                        unsigned short* __restrict__ Xn,        // [T][B][H] bf16 (next-layer input)
                        float* outx)                            // d_out x region (layer 3) or null
{
  __shared__ float zlds[16 * 1024];     // 64 KB swizzled z staging
  __shared__ short hst[16 * 1024];      // 32 KB swizzled h (bf16)
  __shared__ float sG[1024], sB[1024];  // 8 KB
  int tid = threadIdx.x, lane = tid & 63, w = tid >> 6;
  int rb = blockIdx.x >> 4, cb = blockIdx.x & 15;
  int r0 = rb * 16, c0 = cb * 64;
  int m15 = lane & 15, quad = lane >> 4;

  for (int i = tid; i < 1024; i += 256) { sG[i] = lng[i]; sB[i] = lnb[i]; }

  // preload B fragments: wave w covers cols c0+16w..+15; lane holds Wh[n][k0..k0+7]
  v8s bfrag[32];
  {
    const unsigned short* wrow = Whb + (size_t)(c0 + w * 16 + m15) * 1024 + quad * 8;
    #pragma unroll
    for (int ks = 0; ks < 32; ++ks) bfrag[ks] = *(const v8s*)(wrow + ks * 32);
  }
  __syncthreads();

  int myrow = 4 * w + quad;     // phase-B: wave w owns rows 4w..4w+3
  int chunk = m15;              // lane owns 64-col chunk of its row
  float* Zrb = Z + (size_t)rb * 2 * 16 * 1024;
  int* myflags = flags + rb * 16;

  for (int t = 0; t < T_; ++t) {
    // prefetch A[t+1] tile for z production (plain cached loads; A is immutable)
    float apre[4] = {0.f, 0.f, 0.f, 0.f};
    if (t < T_ - 1) {
      const float* ap = A + ((size_t)(t + 1) * B_ + r0) * H_;
      #pragma unroll
      for (int r = 0; r < 4; ++r)
        apre[r] = ap[(size_t)(quad * 4 + r) * H_ + c0 + w * 16 + m15];
    }
    if (t > 0) {
      if (w == 0 && lane < 16) {
        const int* fp = myflags + lane;
        int iters = 0;
        while (__hip_atomic_load(fp, __ATOMIC_RELAXED, __HIP_MEMORY_SCOPE_AGENT) < t) {
          __builtin_amdgcn_s_sleep(1);
          if (++iters > (1 << 21)) break;   // safety valve: garbage beats hang
        }
      }
      __syncthreads();
    }

    // ---- phase A: stage z tile (16 x 1024 fp32) into swizzled LDS, coalesced ----
    if (t == 0) {
      const float* zg = A + (size_t)r0 * H_;          // h_{-1}=0 -> z_0 = A[0]
      #pragma unroll
      for (int row = 0; row < 16; ++row)
        #pragma unroll
        for (int e = 0; e < 4; ++e) {
          int col = e * 256 + tid;
          zlds[zswz(row, col >> 2) + (col & 3)] = zg[(size_t)row * H_ + col];
        }
    } else {
      const float* zg = Zrb + (size_t)(t & 1) * 16 * 1024;
      #pragma unroll
      for (int row = 0; row < 16; ++row)
        #pragma unroll
        for (int e = 0; e < 4; ++e) {
          int col = e * 256 + tid;
          float v = __hip_atomic_load(&zg[(size_t)row * H_ + col],
                                      __ATOMIC_RELAXED, __HIP_MEMORY_SCOPE_AGENT);
          zlds[zswz(row, col >> 2) + (col & 3)] = v;
        }
    }
    __syncthreads();

    // ---- phase B: LN + tanh, stage h (bf16) into swizzled LDS ----
    v4f zreg[16];
    #pragma unroll
    for (int jj = 0; jj < 16; ++jj)
      zreg[jj] = *(const v4f*)&zlds[zswz(myrow, chunk * 16 + jj)];
    float s = 0.f, s2 = 0.f;
    #pragma unroll
    for (int jj = 0; jj < 16; ++jj)
      #pragma unroll
      for (int e = 0; e < 4; ++e) { float v = zreg[jj][e]; s += v; s2 += v * v; }
    #pragma unroll
    for (int m = 1; m < 16; m <<= 1) { s += __shfl_xor(s, m); s2 += __shfl_xor(s2, m); }
    float mu = s * (1.f / 1024.f);
    float var = s2 * (1.f / 1024.f) - mu * mu;
    float rs = rsqrtf(var + LN_EPS);
    #pragma unroll
    for (int g8 = 0; g8 < 8; ++g8) {
      v8s hp;
      #pragma unroll
      for (int e = 0; e < 8; ++e) {
        int colg = chunk * 64 + g8 * 8 + e;
        float zv = zreg[g8 * 2 + (e >> 2)][e & 3];
        float hv = tanh_fast((zv - mu) * rs * sG[colg] + sB[colg]);
        hp[e] = (short)f2bf(hv);
      }
      *(v8s*)&hst[hswz(myrow, chunk * 8 + g8)] = hp;
    }
    __syncthreads();   // hst complete (16 rows x 1024)

    // ---- producer: z'[16 x 64] = h @ Wh^T + A[t+1], publish via agent atomics ----
    if (t < T_ - 1) {
      v4f acc = (v4f){0.f, 0.f, 0.f, 0.f};
      #pragma unroll
      for (int ks = 0; ks < 32; ++ks) {
        v8s a = *(const v8s*)&hst[hswz(m15, ks * 4 + quad)];  // A-frag row=lane&15,k=quad*8+j
        acc = __builtin_amdgcn_mfma_f32_16x16x32_bf16(a, bfrag[ks], acc, 0, 0, 0);
      }
      float* zo = Zrb + (size_t)((t + 1) & 1) * 16 * 1024;
      #pragma unroll
      for (int r = 0; r < 4; ++r)
        __hip_atomic_store(&zo[(size_t)(quad * 4 + r) * H_ + c0 + w * 16 + m15],
                           acc[r] + apre[r], __ATOMIC_RELAXED, __HIP_MEMORY_SCOPE_AGENT);
    }

    // ---- persist own 64-col slice of h (overlaps z' store drain) ----
    {
      int row = tid >> 4, ci = tid & 15;
      int colbase = c0 + ci * 4;
      int kq = colbase >> 3, half = ci & 1;
      const short* hp = &hst[hswz(row, kq) + half * 4];
      union { unsigned short u[4]; uint2 q; } pk;
      pk.u[0] = (unsigned short)hp[0]; pk.u[1] = (unsigned short)hp[1];
      pk.u[2] = (unsigned short)hp[2]; pk.u[3] = (unsigned short)hp[3];
      *(uint2*)(Xn + ((size_t)t * B_ + r0 + row) * H_ + colbase) = pk.q;
      if (outx) {
        float4 f;
        f.x = bf2f(pk.u[0]); f.y = bf2f(pk.u[1]); f.z = bf2f(pk.u[2]); f.w = bf2f(pk.u[3]);
        *(float4*)(outx + ((size_t)(r0 + row) * T_ + t) * H_ + colbase) = f;
      }
    }

    // barrier drains vmcnt(0) for ALL waves (z' stores acked at coherence point),
    // then one thread publishes the flag.
    __syncthreads();
    if (t < T_ - 1 && tid == 0) {
      __builtin_amdgcn_s_waitcnt(0);
      __hip_atomic_store(myflags + cb, t + 1, __ATOMIC_RELAXED, __HIP_MEMORY_SCOPE_AGENT);
    }
  }
}

extern "C" void kernel_launch(void* const* d_in, const int* in_sizes, int n_in,
                              void* d_out, int out_size, void* d_ws, size_t ws_size,
                              hipStream_t stream) {
  const float* inp = (const float*)d_in[0];
  const float* Wx  = (const float*)d_in[1];
  const float* bx  = (const float*)d_in[2];
  const float* Wh  = (const float*)d_in[3];
  const float* lng = (const float*)d_in[4];
  const float* lnb = (const float*)d_in[5];
  const float* Wy  = (const float*)d_in[6];
  const float* by  = (const float*)d_in[7];
  float* out_x = (float*)d_out;
  float* out_y = out_x + (size_t)B_ * T_ * H_;

  char* ws = (char*)d_ws;
  unsigned short* Whb = (unsigned short*)(ws);                       // 8 MB
  unsigned short* Wxb = (unsigned short*)(ws + ((size_t)8 << 20));   // 8 MB
  unsigned short* Wyb = (unsigned short*)(ws + ((size_t)16 << 20));  // 2 MB
  int* flags          = (int*)(ws + ((size_t)18 << 20));             // 1 KB
  float* Z            = (float*)(ws + ((size_t)19 << 20));           // 512 KB
  unsigned short* X   = (unsigned short*)(ws + ((size_t)20 << 20));  // 32 MB
  float* A            = (float*)(ws + ((size_t)52 << 20));           // 64 MB  (total 116 MB)

  hipMemsetAsync(flags, 0, L_ * 64 * sizeof(int), stream);
  k_f2b<<<1024, 256, 0, stream>>>(Wh, Whb, (L_ * H_ * H_) / 4);
  k_f2b<<<1024, 256, 0, stream>>>(Wx, Wxb, (L_ * H_ * H_) / 4);
  k_f2b<<<256, 256, 0, stream>>>(Wy, Wyb, (O_ * H_) / 4);
  k_prep_x<<<B_ * T_, 256, 0, stream>>>(inp, X);

  for (int l = 0; l < L_; ++l) {
    k_gemm<<<1024, 256, 0, stream>>>(X, Wxb + (size_t)l * H_ * H_, bx + (size_t)l * H_, A, 0);
    k_recur<<<64, 256, 0, stream>>>(A, Whb + (size_t)l * H_ * H_,
                                    lng + (size_t)l * H_, lnb + (size_t)l * H_,
                                    Z, flags + l * 64, X,
                                    (l == L_ - 1) ? out_x : (float*)nullptr);
  }
  k_gemm<<<1024, 256, 0, stream>>>(X, Wyb, by, out_y, 1);
}

// Round 3
// 8839.429 us; speedup vs baseline: 2.6643x; 2.6643x over previous
//
#include <hip/hip_runtime.h>
#include <stdint.h>

#define B_ 64
#define T_ 256
#define H_ 1024
#define L_ 4
#define O_ 1024
#define LN_EPS 1e-5f

typedef short v8s __attribute__((ext_vector_type(8)));
typedef float v4f __attribute__((ext_vector_type(4)));

__device__ __forceinline__ unsigned short f2bf(float f) {
  union { float f; unsigned u; } v; v.f = f;
  unsigned r = (v.u + 0x7FFFu + ((v.u >> 16) & 1u)) >> 16;  // RNE
  return (unsigned short)r;
}
__device__ __forceinline__ float bf2f(unsigned short u) {
  union { unsigned u; float f; } v; v.u = ((unsigned)u) << 16; return v.f;
}
__device__ __forceinline__ float tanh_fast(float x) {
  float e = __expf(2.0f * x);
  return 1.0f - 2.0f / (e + 1.0f);   // -> -1/+1 correctly at +-inf
}

// Swizzled LDS index for h tile (bf16, 16B granules), bijective per row.
__device__ __forceinline__ int hswz(int row, int kq) {
  return ((row << 7) + ((kq ^ (kq >> 4) ^ row) & 127)) << 3;
}

// ---------------- fp32 -> bf16 bulk convert (vec4) ----------------
__global__ void k_f2b(const float* __restrict__ src, unsigned short* __restrict__ dst, int n4) {
  int i = blockIdx.x * blockDim.x + threadIdx.x;
  int stride = gridDim.x * blockDim.x;
  for (; i < n4; i += stride) {
    float4 v = *(const float4*)(src + 4 * (size_t)i);
    union { unsigned short u[4]; uint2 q; } p;
    p.u[0] = f2bf(v.x); p.u[1] = f2bf(v.y); p.u[2] = f2bf(v.z); p.u[3] = f2bf(v.w);
    *(uint2*)(dst + 4 * (size_t)i) = p.q;
  }
}

// ------------- input [B][T][H] f32 -> X [T][B][H] bf16 -------------
__global__ void k_prep_x(const float* __restrict__ in, unsigned short* __restrict__ X) {
  int row = blockIdx.x;            // row = b*T + t
  int b = row >> 8, t = row & 255;
  const float* src = in + (size_t)row * H_;
  unsigned short* dst = X + ((size_t)t * B_ + b) * H_;
  for (int j = threadIdx.x; j < H_ / 4; j += blockDim.x) {
    float4 v = *(const float4*)(src + 4 * j);
    union { unsigned short u[4]; uint2 q; } p;
    p.u[0] = f2bf(v.x); p.u[1] = f2bf(v.y); p.u[2] = f2bf(v.z); p.u[3] = f2bf(v.w);
    *(uint2*)(dst + 4 * j) = p.q;
  }
}

// ---------------- bf16 GEMM: C[M=16384][1024] = X @ W^T + bias ----------------
__launch_bounds__(256, 2)
__global__ void k_gemm(const unsigned short* __restrict__ Xb,
                       const unsigned short* __restrict__ Wb,
                       const float* __restrict__ bias,
                       float* __restrict__ Cout, int swap_rows) {
  __shared__ short As[128][40];
  __shared__ short Bs[128][40];
  int bm = blockIdx.x >> 3, bn = blockIdx.x & 7;
  int row0 = bm * 128, col0 = bn * 128;
  int tid = threadIdx.x, lane = tid & 63, w = tid >> 6;
  int wm = w >> 1, wn = w & 1;
  int m15 = lane & 15, quad = lane >> 4;
  v4f acc[4][4];
  #pragma unroll
  for (int a = 0; a < 4; ++a)
    #pragma unroll
    for (int b = 0; b < 4; ++b) acc[a][b] = (v4f){0.f, 0.f, 0.f, 0.f};

  int srow = tid >> 1, sseg = tid & 1;
  const unsigned short* gA = Xb + (size_t)(row0 + srow) * 1024 + sseg * 16;
  const unsigned short* gB = Wb + (size_t)(col0 + srow) * 1024 + sseg * 16;

  for (int kb = 0; kb < 32; ++kb) {
    v8s a0 = *(const v8s*)(gA + kb * 32);
    v8s a1 = *(const v8s*)(gA + kb * 32 + 8);
    v8s b0 = *(const v8s*)(gB + kb * 32);
    v8s b1 = *(const v8s*)(gB + kb * 32 + 8);
    *(v8s*)&As[srow][sseg * 16]     = a0;
    *(v8s*)&As[srow][sseg * 16 + 8] = a1;
    *(v8s*)&Bs[srow][sseg * 16]     = b0;
    *(v8s*)&Bs[srow][sseg * 16 + 8] = b1;
    __syncthreads();
    v8s af[4], bfr[4];
    #pragma unroll
    for (int mt = 0; mt < 4; ++mt) af[mt]  = *(v8s*)&As[wm * 64 + mt * 16 + m15][quad * 8];
    #pragma unroll
    for (int nt = 0; nt < 4; ++nt) bfr[nt] = *(v8s*)&Bs[wn * 64 + nt * 16 + m15][quad * 8];
    #pragma unroll
    for (int mt = 0; mt < 4; ++mt)
      #pragma unroll
      for (int nt = 0; nt < 4; ++nt)
        acc[mt][nt] = __builtin_amdgcn_mfma_f32_16x16x32_bf16(af[mt], bfr[nt], acc[mt][nt], 0, 0, 0);
    __syncthreads();
  }
  #pragma unroll
  for (int mt = 0; mt < 4; ++mt) {
    #pragma unroll
    for (int nt = 0; nt < 4; ++nt) {
      int col = col0 + wn * 64 + nt * 16 + m15;
      float bv = bias[col];
      #pragma unroll
      for (int r = 0; r < 4; ++r) {
        int row = row0 + wm * 64 + mt * 16 + quad * 4 + r;
        int orow = swap_rows ? ((row & 63) * 256 + (row >> 6)) : row;
        Cout[(size_t)orow * 1024 + col] = acc[mt][nt][r] + bv;
      }
    }
  }
}

// ---------------- persistent recurrent kernel (one layer) ----------------
// 64 WGs = 4 row-blocks(16 rows) x 16 col-blocks(64 cols). Wh frags in VGPRs.
// Exchange protocol (fence-free):
//   producer: z' via relaxed agent-scope atomic stores (write-through to L3)
//             -> __syncthreads (vmcnt(0) drains all waves) -> flag atomic store
//   consumer: poll flag (atomic load) -> plain VECTORIZED float4 loads of z.
// Plain cached loads are safe because Z addresses are MONOTONIC in t (never
// reused within a dispatch -> guaranteed L2 miss -> fresh from L3); cross-
// dispatch reuse is safe (kernel boundaries writeback+invalidate caches).
__launch_bounds__(256, 1)
__global__ void k_recur(const float* __restrict__ A,            // [T][B][H] fp32 (x@Wx^T + bx)
                        const unsigned short* __restrict__ Whb, // [H][H] bf16, this layer
                        const float* __restrict__ lng, const float* __restrict__ lnb,
                        float* Z,                               // [T][4 rb][16][1024] fp32
                        int* flags,                             // [64]: flag[rb*16+cb]
                        unsigned short* __restrict__ Xn,        // [T][B][H] bf16
                        float* outx)                            // d_out x region or null
{
  __shared__ short hst[16 * 1024];      // 32 KB swizzled h (bf16)
  __shared__ float sG[1024], sB[1024];  // 8 KB
  int tid = threadIdx.x, lane = tid & 63, w = tid >> 6;
  int rb = blockIdx.x >> 4, cb = blockIdx.x & 15;
  int r0 = rb * 16, c0 = cb * 64;
  int m15 = lane & 15, quad = lane >> 4;

  for (int i = tid; i < 1024; i += 256) { sG[i] = lng[i]; sB[i] = lnb[i]; }

  // preload B fragments: wave w covers cols c0+16w..+15; lane holds Wh[n][k0..k0+7]
  v8s bfrag[32];
  {
    const unsigned short* wrow = Whb + (size_t)(c0 + w * 16 + m15) * 1024 + quad * 8;
    #pragma unroll
    for (int ks = 0; ks < 32; ++ks) bfrag[ks] = *(const v8s*)(wrow + ks * 32);
  }
  __syncthreads();

  int myrow = 4 * w + quad;     // LN phase: wave w owns rows 4w..4w+3
  int chunk = m15;              // lane owns 64-col chunk of its row
  int* myflags = flags + rb * 16;

  for (int t = 0; t < T_; ++t) {
    // prefetch A[t+1] tile (plain cached; A immutable) — overlaps the flag wait
    float apre[4] = {0.f, 0.f, 0.f, 0.f};
    if (t < T_ - 1) {
      const float* ap = A + ((size_t)(t + 1) * B_ + r0) * H_;
      #pragma unroll
      for (int r = 0; r < 4; ++r)
        apre[r] = ap[(size_t)(quad * 4 + r) * H_ + c0 + w * 16 + m15];
    }
    if (t > 0) {
      if (w == 0 && lane < 16) {
        const int* fp = myflags + lane;
        int iters = 0;
        while (__hip_atomic_load(fp, __ATOMIC_RELAXED, __HIP_MEMORY_SCOPE_AGENT) < t) {
          __builtin_amdgcn_s_sleep(1);
          if (++iters > (1 << 20)) break;   // safety valve: garbage beats hang
        }
      }
      __syncthreads();   // also protects hst (persist-read of t-1 done)
    }

    // ---- z load: register-direct, vectorized, plain cached ----
    const float* zsrc = (t == 0) ? (A + (size_t)r0 * H_)                 // z_0 = A[0]
                                 : (Z + ((size_t)t * 4 + rb) * 16 * 1024);
    float4 zr4[16];
    {
      const float4* zp = (const float4*)(zsrc + (size_t)myrow * H_ + chunk * 64);
      #pragma unroll
      for (int j = 0; j < 16; ++j) zr4[j] = zp[j];
    }

    // ---- LN stats over the 16 lanes sharing this row ----
    float s = 0.f, s2 = 0.f;
    #pragma unroll
    for (int j = 0; j < 16; ++j) {
      s  += zr4[j].x + zr4[j].y + zr4[j].z + zr4[j].w;
      s2 += zr4[j].x * zr4[j].x + zr4[j].y * zr4[j].y
          + zr4[j].z * zr4[j].z + zr4[j].w * zr4[j].w;
    }
    #pragma unroll
    for (int m = 1; m < 16; m <<= 1) { s += __shfl_xor(s, m); s2 += __shfl_xor(s2, m); }
    float mu = s * (1.f / 1024.f);
    float var = s2 * (1.f / 1024.f) - mu * mu;
    float rs = rsqrtf(var + LN_EPS);

    // ---- h = tanh(LN(z)) -> swizzled LDS (bf16) ----
    #pragma unroll
    for (int g8 = 0; g8 < 8; ++g8) {
      v8s hp;
      #pragma unroll
      for (int e = 0; e < 8; ++e) {
        int colg = chunk * 64 + g8 * 8 + e;
        const float4& q = zr4[g8 * 2 + (e >> 2)];
        float zv = (e & 2) ? ((e & 1) ? q.w : q.z) : ((e & 1) ? q.y : q.x);
        float hv = tanh_fast((zv - mu) * rs * sG[colg] + sB[colg]);
        hp[e] = (short)f2bf(hv);
      }
      *(v8s*)&hst[hswz(myrow, chunk * 8 + g8)] = hp;
    }
    __syncthreads();   // hst complete (16 rows x 1024)

    if (t < T_ - 1) {
      // ---- z'[16 x 64] = h @ Wh^T + A[t+1]; publish write-through ----
      v4f acc = (v4f){0.f, 0.f, 0.f, 0.f};
      #pragma unroll
      for (int ks = 0; ks < 32; ++ks) {
        v8s a = *(const v8s*)&hst[hswz(m15, ks * 4 + quad)];  // A-frag row=lane&15,k=quad*8+j
        acc = __builtin_amdgcn_mfma_f32_16x16x32_bf16(a, bfrag[ks], acc, 0, 0, 0);
      }
      float* zo = Z + ((size_t)(t + 1) * 4 + rb) * 16 * 1024;
      #pragma unroll
      for (int r = 0; r < 4; ++r)
        __hip_atomic_store(&zo[(size_t)(quad * 4 + r) * H_ + c0 + w * 16 + m15],
                           acc[r] + apre[r], __ATOMIC_RELAXED, __HIP_MEMORY_SCOPE_AGENT);
      __syncthreads();   // vmcnt(0) for ALL waves: z' acked at coherence point
      if (tid == 0)
        __hip_atomic_store(myflags + cb, t + 1, __ATOMIC_RELAXED, __HIP_MEMORY_SCOPE_AGENT);
    }

    // ---- persist own 64-col slice of h (off the critical path) ----
    {
      int row = tid >> 4, ci = tid & 15;
      int colbase = c0 + ci * 4;
      int kq = colbase >> 3, half = ci & 1;
      const short* hp = &hst[hswz(row, kq) + half * 4];
      union { unsigned short u[4]; uint2 q; } pk;
      pk.u[0] = (unsigned short)hp[0]; pk.u[1] = (unsigned short)hp[1];
      pk.u[2] = (unsigned short)hp[2]; pk.u[3] = (unsigned short)hp[3];
      *(uint2*)(Xn + ((size_t)t * B_ + r0 + row) * H_ + colbase) = pk.q;
      if (outx) {
        float4 f;
        f.x = bf2f(pk.u[0]); f.y = bf2f(pk.u[1]); f.z = bf2f(pk.u[2]); f.w = bf2f(pk.u[3]);
        *(float4*)(outx + ((size_t)(r0 + row) * T_ + t) * H_ + colbase) = f;
      }
    }
    // hst stays valid for the persist reads until next iteration's poll barrier
  }
}

extern "C" void kernel_launch(void* const* d_in, const int* in_sizes, int n_in,
                              void* d_out, int out_size, void* d_ws, size_t ws_size,
                              hipStream_t stream) {
  const float* inp = (const float*)d_in[0];
  const float* Wx  = (const float*)d_in[1];
  const float* bx  = (const float*)d_in[2];
  const float* Wh  = (const float*)d_in[3];
  const float* lng = (const float*)d_in[4];
  const float* lnb = (const float*)d_in[5];
  const float* Wy  = (const float*)d_in[6];
  const float* by  = (const float*)d_in[7];
  float* out_x = (float*)d_out;
  float* out_y = out_x + (size_t)B_ * T_ * H_;

  char* ws = (char*)d_ws;
  unsigned short* Whb = (unsigned short*)(ws);                        // 8 MB
  unsigned short* Wxb = (unsigned short*)(ws + ((size_t)8 << 20));    // 8 MB
  unsigned short* Wyb = (unsigned short*)(ws + ((size_t)16 << 20));   // 2 MB
  int* flags          = (int*)(ws + ((size_t)18 << 20));              // 1 KB
  float* A            = (float*)(ws + ((size_t)19 << 20));            // 64 MB
  unsigned short* X   = (unsigned short*)(ws + ((size_t)83 << 20));   // 32 MB
  float* Z            = (float*)(ws + ((size_t)115 << 20));           // 64 MB (monotonic, total 179 MB)

  hipMemsetAsync(flags, 0, L_ * 64 * sizeof(int), stream);
  k_f2b<<<1024, 256, 0, stream>>>(Wh, Whb, (L_ * H_ * H_) / 4);
  k_f2b<<<1024, 256, 0, stream>>>(Wx, Wxb, (L_ * H_ * H_) / 4);
  k_f2b<<<256, 256, 0, stream>>>(Wy, Wyb, (O_ * H_) / 4);
  k_prep_x<<<B_ * T_, 256, 0, stream>>>(inp, X);

  for (int l = 0; l < L_; ++l) {
    k_gemm<<<1024, 256, 0, stream>>>(X, Wxb + (size_t)l * H_ * H_, bx + (size_t)l * H_, A, 0);
    k_recur<<<64, 256, 0, stream>>>(A, Whb + (size_t)l * H_ * H_,
                                    lng + (size_t)l * H_, lnb + (size_t)l * H_,
                                    Z, flags + l * 64, X,
                                    (l == L_ - 1) ? out_x : (float*)nullptr);
  }
  k_gemm<<<1024, 256, 0, stream>>>(X, Wyb, by, out_y, 1);
}